// Round 15
// baseline (2153.554 us; speedup 1.0000x reference)
//
#include <hip/hip_runtime.h>
#include <hip/hip_bf16.h>
#include <math.h>

#define BS   4096
#define ZD   512
#define HIDN 1024
#define ZINN 128
#define NST  32
#define NP   3072   // 3*HIDN, gate-interleaved column space (96 = 3x32 groups)

typedef unsigned short u16;
typedef __bf16 bf16x8 __attribute__((ext_vector_type(8)));
typedef _Float16 f16x8 __attribute__((ext_vector_type(8)));
typedef float f32x4 __attribute__((ext_vector_type(4)));
typedef float f32x16 __attribute__((ext_vector_type(16)));

static __device__ __forceinline__ u16 bf_bits(float v) {
  __bf16 b = (__bf16)v;
  return __builtin_bit_cast(unsigned short, b);
}
static __device__ __forceinline__ float bf_val(float v) {
  return (float)(__bf16)v;
}
static __device__ __forceinline__ u16 h16_bits(float v) {
  _Float16 h = (_Float16)v;
  return __builtin_bit_cast(unsigned short, h);
}
static __device__ __forceinline__ float h16_val_bits(u16 b) {
  return (float)__builtin_bit_cast(_Float16, b);
}

// async global -> LDS, 16 bytes per lane. LDS dest = wave-uniform base + lane*16.
static __device__ __forceinline__ void ld_lds16(const u16* g, u16* l) {
  __builtin_amdgcn_global_load_lds(
      (const __attribute__((address_space(1))) void*)g,
      (__attribute__((address_space(3))) void*)l, 16, 0, 0);
}

// W' row w -> original W_hh/W_ih row. 32-granular interleave for 32x32 MFMA:
// w = g*96 + j*32 + m  ->  j*1024 + g*32 + m   (j = gate r/u/n, m = h-col within group)
static __device__ __forceinline__ int r_orig(int w) {
  const int g = w / 96;
  const int rem = w - g * 96;
  const int j = rem >> 5, m = rem & 31;
  return j * 1024 + g * 32 + m;
}

// ---------------- fragment-major packed layouts (single f16 pass) ----------------
// 64-q (K=1024 operands): [rg = row/32][q = k/16][64 lanes x 8 u16].
// Lane slot l = ((k>>3)&1)*32 + (row&31) = the mfma_32x32x16 fragment order ->
// ds_read_b128 / global_load_dwordx4 at base+lane*16 IS the fragment (0 conflicts,
// verified v6-v14); global_load_lds staging is linear 1KB blocks.
static __device__ __forceinline__ size_t pk_off(int row, int col) {
  return ((size_t)(row >> 5) * 64 + (col >> 4)) * 512 +
         (((col >> 3) & 1) * 32 + (row & 31)) * 8 + (col & 7);
}
// 8-q variant (K=128 operands: zin / Wihz)
static __device__ __forceinline__ size_t pkz_off(int row, int col) {
  return ((size_t)(row >> 5) * 8 + (col >> 4)) * 512 +
         (((col >> 3) & 1) * 32 + (row & 31)) * 8 + (col & 7);
}

// ---------------- prep kernels ----------------

__global__ void k_split(const float* __restrict__ s, u16* __restrict__ hi,
                        u16* __restrict__ lo, int n) {
  int i = blockIdx.x * 256 + threadIdx.x;
  if (i >= n) return;
  float v = s[i];
  float h = bf_val(v);
  hi[i] = bf_bits(v);
  lo[i] = bf_bits(v - h);
}

// W_hh -> fragment-major single-pass f16 Bpk with gate-interleaved row reorder
__global__ void k_pack_whh(const float* __restrict__ W_hh, u16* __restrict__ Bpk) {
  int i = blockIdx.x * 256 + threadIdx.x;
  if (i >= NP * HIDN) return;
  const int w = i >> 10, k = i & 1023;
  const float v = W_hh[(size_t)r_orig(w) * HIDN + k];
  Bpk[pk_off(w, k)] = h16_bits(v);
}

// W_ih[:,3:131] -> f16 frag-major Wpk (reordered rows); [:,0:3] -> wtok; cb0
__global__ void k_prep_wih(const float* __restrict__ W_ih, const float* __restrict__ b_ih,
                           const float* __restrict__ b_hh,
                           u16* __restrict__ Wpk,
                           float* __restrict__ wtok, float* __restrict__ cb0) {
  int i = blockIdx.x * 256 + threadIdx.x;
  if (i < NP * 128) {
    const int w = i >> 7, c = i & 127;
    const float v = W_ih[r_orig(w) * 131 + 3 + c];
    Wpk[pkz_off(w, c)] = h16_bits(v);
  }
  if (i < NP * 3) {
    const int w = i / 3, s = i - w * 3;
    wtok[i] = W_ih[r_orig(w) * 131 + s];
  }
  if (i < NP) {
    const int r = r_orig(i);
    cb0[i] = b_ih[r] + (r < 2048 ? b_hh[r] : 0.0f);
  }
}

__global__ void k_token_init(const float* __restrict__ init_input, float* __restrict__ token) {
  int i = blockIdx.x * 256 + threadIdx.x;
  if (i < BS * 4) token[i] = ((i & 3) < 3) ? init_input[i & 3] : 0.0f;
}

// ---------------- generic split-3 GEMM (prep only): C = A*B^T (+bias) ----------------
// OUTMODE: 2 = 64-q f16 Apk (h0);  3 = 8-q f16 Zpk (zin)
template <int OUTMODE>
__global__ __launch_bounds__(256) void k_gemm(
    const u16* __restrict__ Ahi, const u16* __restrict__ Alo,
    const u16* __restrict__ Bhi, const u16* __restrict__ Blo,
    const float* __restrict__ bias,
    u16* __restrict__ Apk, int N, int K) {
  __shared__ __align__(16) u16 sAhi[128 * 64];
  __shared__ __align__(16) u16 sAlo[128 * 64];
  __shared__ __align__(16) u16 sBhi[128 * 64];
  __shared__ __align__(16) u16 sBlo[128 * 64];

  const int t = threadIdx.x;
  const int row0 = blockIdx.y * 128, col0 = blockIdx.x * 128;
  const int wave = t >> 6, lane = t & 63;
  const int w64 = wave * 64;
  const int wm = (wave & 1) * 64, wn = (wave >> 1) * 64;
  const int lm = lane & 15, lq = lane >> 4;
  const int pb = lm & 7;

  f32x4 acc[4][4] = {};

  int sm[4], skc[4], sub[4];
#pragma unroll
  for (int i = 0; i < 4; ++i) {
    const int u = i * 256 + t;
    sm[i] = u >> 3;
    skc[i] = (u & 7) ^ (sm[i] & 7);
    sub[i] = (i * 256 + w64) * 8;
  }

  const int nk = K >> 6;
  for (int kt = 0; kt < nk; ++kt) {
    const int k0 = kt << 6;
    __syncthreads();
#pragma unroll
    for (int i = 0; i < 4; ++i) {
      const size_t ga = (size_t)(row0 + sm[i]) * K + k0 + skc[i] * 8;
      const size_t gb = (size_t)(col0 + sm[i]) * K + k0 + skc[i] * 8;
      ld_lds16(Ahi + ga, &sAhi[sub[i]]);
      ld_lds16(Alo + ga, &sAlo[sub[i]]);
      ld_lds16(Bhi + gb, &sBhi[sub[i]]);
      ld_lds16(Blo + gb, &sBlo[sub[i]]);
    }
    __syncthreads();
#pragma unroll
    for (int kk = 0; kk < 2; ++kk) {
      const int pos = ((kk * 4 + lq) ^ pb) * 8;
      bf16x8 ah[4], al[4], bh[4], bl[4];
#pragma unroll
      for (int i = 0; i < 4; ++i) {
        const int ma = (wm + i * 16 + lm) * 64;
        const int mb = (wn + i * 16 + lm) * 64;
        ah[i] = *(const bf16x8*)&sAhi[ma + pos];
        al[i] = *(const bf16x8*)&sAlo[ma + pos];
        bh[i] = *(const bf16x8*)&sBhi[mb + pos];
        bl[i] = *(const bf16x8*)&sBlo[mb + pos];
      }
#pragma unroll
      for (int i = 0; i < 4; ++i)
#pragma unroll
        for (int j = 0; j < 4; ++j) {
          acc[i][j] = __builtin_amdgcn_mfma_f32_16x16x32_bf16(ah[i], bh[j], acc[i][j], 0, 0, 0);
          acc[i][j] = __builtin_amdgcn_mfma_f32_16x16x32_bf16(al[i], bh[j], acc[i][j], 0, 0, 0);
          acc[i][j] = __builtin_amdgcn_mfma_f32_16x16x32_bf16(ah[i], bl[j], acc[i][j], 0, 0, 0);
        }
    }
  }

#pragma unroll
  for (int i = 0; i < 4; ++i) {
    const int grow = row0 + wm + i * 16 + lq * 4;
#pragma unroll
    for (int j = 0; j < 4; ++j) {
      const int gcol = col0 + wn + j * 16 + lm;
      const float bs = bias ? bias[gcol] : 0.0f;
#pragma unroll
      for (int d = 0; d < 4; ++d) {
        const float v = acc[i][j][d] + bs;
        if (OUTMODE == 2) {
          Apk[pk_off(grow + d, gcol)] = h16_bits(v);
        }
        if (OUTMODE == 3) {
          Apk[pkz_off(grow + d, gcol)] = h16_bits(v);
        }
      }
    }
  }
}

// ---------------- fused gh+gi GEMM + GRU gate kernel (v15: B direct global->reg) ----------------
// v14 skeleton (BK=64, 2 blk/CU, 8 waves 4Mx2N, one __syncthreads per tile, Z-fold,
// f16-only state). NEW: the B/W operand is read DIRECTLY from global to registers —
// the packed layout IS the fragment layout, so global_load_dwordx4 at base+lane*16
// yields the MFMA operand. B is L3-resident (6MB) and L2-hot; cost = 4x L2 traffic
// (each M-wave fetches it), gain = -2304 cyc/CU/tile of LDS reads, -24KB/tile staging,
// LDS shrinks to 32KB. A (block-private) stays LDS-staged via global_load_lds.

#define SZA8 (128 * 64)   // 8192 u16/buf: [4 rg][4 q][512]
#define MF8(a, b, c) c = __builtin_amdgcn_mfma_f32_32x32x16_f16(a, b, c, 0, 0, 0)

__global__ __launch_bounds__(512, 4) void k_fused15(
    const u16* __restrict__ Apk,   // f16 frag-major h [128 rg][64 q][512]
    const u16* __restrict__ Bpk,   // f16 frag-major Whh' [96 rg][64 q][512]
    const u16* __restrict__ Zpk,   // f16 frag-major zin [128 rg][8 q][512]
    const u16* __restrict__ Wpk,   // f16 frag-major Wihz' [96 rg][8 q][512]
    const float* __restrict__ token,
    const float* __restrict__ wtok,
    const float* __restrict__ cb0,
    const float* __restrict__ b_hh,
    u16* __restrict__ Apk_out) {
  __shared__ __align__(16) u16 sA[2 * SZA8];

  const int t = threadIdx.x;
  const int wave = t >> 6, lane = t & 63;
  const int row0 = blockIdx.y * 128;
  const int colW0 = blockIdx.x * 192;
  const int wm = (wave >> 1) * 32;   // 4 M-waves x 32 rows
  const int wn = (wave & 1) * 96;    // 2 N-waves x 96 W-rows (one gate-triple group)
  const int lr = lane & 31, lh = lane >> 5;
  const int l8 = lane * 8;

  f32x16 acc0 = {}, acc1 = {}, acc2 = {}, acc3 = {};

  // ---- A staging: 16 pass-blocks per BK=64 tile, 2 loads/wave ----
  const u16* asrc = Apk + ((size_t)((row0 >> 5) + (wave >> 1)) * 64 + (wave & 1) * 2) * 512 + l8;
  const u16* azb = Zpk + ((size_t)((row0 >> 5) + (wave >> 1)) * 8 + (wave & 1) * 2) * 512 + l8;
  const int aw = (wave >> 1) * 2048 + (wave & 1) * 1024;

#define STAGE(kt_, ab)                                                \
  ld_lds16(asrc + (size_t)(kt_) * 2048,       &sA[(ab) + aw]);        \
  ld_lds16(asrc + (size_t)(kt_) * 2048 + 512, &sA[(ab) + aw + 512]);

#define STAGE_Z(zt_, ab)                                              \
  ld_lds16(azb + (zt_) * 2048,       &sA[(ab) + aw]);                 \
  ld_lds16(azb + (zt_) * 2048 + 512, &sA[(ab) + aw + 512]);

  // ---- B direct-load bases (per-wave gate-triple group; fragment == 1KB block) ----
  const int rgB = (colW0 >> 5) + (wave & 1) * 3;
  const u16* Bg0 = Bpk + ((size_t)(rgB + 0) * 64) * 512 + l8;
  const u16* Bg1 = Bpk + ((size_t)(rgB + 1) * 64) * 512 + l8;
  const u16* Bg2 = Bpk + ((size_t)(rgB + 2) * 64) * 512 + l8;
  const u16* Wg0 = Wpk + ((size_t)(rgB + 0) * 8) * 512 + l8;
  const u16* Wg1 = Wpk + ((size_t)(rgB + 1) * 8) * 512 + l8;
  const u16* Wg2 = Wpk + ((size_t)(rgB + 2) * 8) * 512 + l8;

  // A fragment read base (lane-linear)
  const int agA = (wave >> 1) * 2048;    // + kk*512

  STAGE(0, 0);
  __syncthreads();

#pragma unroll 1
  for (int kt = 0; kt < 16; ++kt) {
    const int ab = (kt & 1) ? SZA8 : 0;
    const int an = (kt & 1) ? 0 : SZA8;
    if (kt < 15) { STAGE(kt + 1, an); }
    else         { STAGE_Z(0, an); }
#pragma unroll
    for (int kk = 0; kk < 4; ++kk) {
      const size_t q = (size_t)(kt * 4 + kk) * 512;
      const f16x8 a = *(const f16x8*)&sA[ab + agA + kk * 512 + l8];
      const f16x8 b0 = *(const f16x8*)&Bg0[q];
      const f16x8 b1 = *(const f16x8*)&Bg1[q];
      const f16x8 b2 = *(const f16x8*)&Bg2[q];
      MF8(a, b0, acc0); MF8(a, b1, acc1); MF8(a, b2, acc2);
    }
    __syncthreads();
  }
  // ---- Z tile 0 (zin cols 0..63) in buf0; n-gate -> acc3 ----
  STAGE_Z(1, SZA8);
#pragma unroll
  for (int kk = 0; kk < 4; ++kk) {
    const size_t q = (size_t)kk * 512;
    const f16x8 a = *(const f16x8*)&sA[agA + kk * 512 + l8];
    const f16x8 b0 = *(const f16x8*)&Wg0[q];
    const f16x8 b1 = *(const f16x8*)&Wg1[q];
    const f16x8 b2 = *(const f16x8*)&Wg2[q];
    MF8(a, b0, acc0); MF8(a, b1, acc1); MF8(a, b2, acc3);
  }
  __syncthreads();
  // ---- Z tile 1 (zin cols 64..127) in buf1 ----
#pragma unroll
  for (int kk = 0; kk < 4; ++kk) {
    const size_t q = (size_t)(4 + kk) * 512;
    const f16x8 a = *(const f16x8*)&sA[SZA8 + agA + kk * 512 + l8];
    const f16x8 b0 = *(const f16x8*)&Wg0[q];
    const f16x8 b1 = *(const f16x8*)&Wg1[q];
    const f16x8 b2 = *(const f16x8*)&Wg2[q];
    MF8(a, b0, acc0); MF8(a, b1, acc1); MF8(a, b2, acc3);
  }
#undef STAGE
#undef STAGE_Z

  // ---- fused GRU epilogue (f32 math; f16 carry) ----
  const int w0 = colW0 + wn + lr;                  // W'-row of r-gate
  const int c = ((colW0 + wn) / 96) * 32 + lr;     // h-col
  float wt[3][3];
#pragma unroll
  for (int j = 0; j < 3; ++j) {
    wt[j][0] = wtok[(w0 + j * 32) * 3 + 0];
    wt[j][1] = wtok[(w0 + j * 32) * 3 + 1];
    wt[j][2] = wtok[(w0 + j * 32) * 3 + 2];
  }
  const float cbr = cb0[w0], cbu = cb0[w0 + 32], cbn = cb0[w0 + 64];
  const float bnn = b_hh[2048 + c];
  const int cq = c >> 4, ckh = (c >> 3) & 1, ce = c & 7;
#pragma unroll
  for (int d = 0; d < 16; ++d) {
    const int row = row0 + wm + 4 * lh + (d & 3) + 8 * (d >> 2);
    const float4 tk = *(const float4*)&token[row * 4];
    const float pr = cbr + acc0[d] + tk.x * wt[0][0] + tk.y * wt[0][1] + tk.z * wt[0][2];
    const float pu = cbu + acc1[d] + tk.x * wt[1][0] + tk.y * wt[1][1] + tk.z * wt[1][2];
    const float pin = cbn + acc3[d] + tk.x * wt[2][0] + tk.y * wt[2][1] + tk.z * wt[2][2];
    const float hn = acc2[d] + bnn;
    const float r = 1.0f / (1.0f + expf(-pr));
    const float u = 1.0f / (1.0f + expf(-pu));
    const float n = tanhf(pin + r * hn);
    const size_t poff = ((size_t)(row >> 5) * 64 + cq) * 512 + (ckh * 32 + (row & 31)) * 8 + ce;
    const float ho = h16_val_bits(Apk[poff]);
    const float hv = (1.0f - u) * n + u * ho;
    Apk_out[poff] = h16_bits(hv);
  }
}
#undef MF8

// ---------------- per-step output kernel (reads packed f16 h; v11-proven) ----------------
__global__ __launch_bounds__(256) void k_out(
    const u16* __restrict__ Apk, const float* __restrict__ W_out,
    const float* __restrict__ b_out,
    float* __restrict__ out, float* __restrict__ token, int step) {
  const int wave = threadIdx.x >> 6, lane = threadIdx.x & 63;
  const int row = blockIdx.x * 4 + wave;
  const u16* base = Apk + (size_t)(row >> 5) * 64 * 512 + (row & 31) * 8;
  float s0 = 0.f, s1 = 0.f, s2 = 0.f;
#pragma unroll
  for (int cc = 0; cc < 2; ++cc) {
    const int ch = lane + cc * 64;   // 16B chunk id, k = ch*8 + e
    const f16x8 hv = *(const f16x8*)&base[(ch >> 1) * 512 + (ch & 1) * 256];
    const int k0 = ch * 8;
#pragma unroll
    for (int e = 0; e < 8; ++e) {
      const float hf = (float)hv[e];
      s0 += hf * W_out[k0 + e];
      s1 += hf * W_out[1024 + k0 + e];
      s2 += hf * W_out[2048 + k0 + e];
    }
  }
#pragma unroll
  for (int off = 32; off > 0; off >>= 1) {
    s0 += __shfl_xor(s0, off, 64);
    s1 += __shfl_xor(s1, off, 64);
    s2 += __shfl_xor(s2, off, 64);
  }
  if (lane == 0) {
    const float o0 = s0 + b_out[0];
    const float o1 = s1 + b_out[1];
    const float o2 = s2 + b_out[2];
    const float bass = 1.0f / (1.0f + expf(-o0));
    const float rhy = 1.0f / (1.0f + expf(-o2));
    const size_t ob = ((size_t)row * NST + step) * 3;
    out[ob + 0] = bass;
    out[ob + 1] = o1;
    out[ob + 2] = rhy;
    token[row * 4 + 0] = bass;
    token[row * 4 + 1] = o1;
    token[row * 4 + 2] = (rhy > 0.5f) ? 1.0f : 0.0f;
  }
}

// ---------------- host ----------------
extern "C" void kernel_launch(void* const* d_in, const int* in_sizes, int n_in,
                              void* d_out, int out_size, void* d_ws, size_t ws_size,
                              hipStream_t stream) {
  const float* z = (const float*)d_in[0];
  const float* W_zh = (const float*)d_in[3];
  const float* b_zh = (const float*)d_in[4];
  const float* W_zi = (const float*)d_in[5];
  const float* b_zi = (const float*)d_in[6];
  const float* W_ih = (const float*)d_in[7];
  const float* b_ih = (const float*)d_in[8];
  const float* W_hh = (const float*)d_in[9];
  const float* b_hh = (const float*)d_in[10];
  const float* W_out = (const float*)d_in[11];
  const float* b_out = (const float*)d_in[12];
  const float* init_input = (const float*)d_in[13];
  float* out = (float*)d_out;

  char* p = (char*)d_ws;
  auto alloc = [&](size_t bytes) {
    char* q = p;
    p += (bytes + 255) & ~(size_t)255;
    return q;
  };
  u16* Apk[2];
  for (int s = 0; s < 2; ++s) {
    Apk[s] = (u16*)alloc((size_t)BS * 1024 * 2);
  }
  u16* Bpk = (u16*)alloc((size_t)NP * 1024 * 2);
  u16* Zpk = (u16*)alloc((size_t)BS * 128 * 2);
  u16* Wpk = (u16*)alloc((size_t)NP * 128 * 2);
  u16* z_hi = (u16*)alloc((size_t)BS * ZD * 2);
  u16* z_lo = (u16*)alloc((size_t)BS * ZD * 2);
  u16* Wzh_hi = (u16*)alloc((size_t)HIDN * ZD * 2);
  u16* Wzh_lo = (u16*)alloc((size_t)HIDN * ZD * 2);
  u16* Wzi_hi = (u16*)alloc((size_t)ZINN * ZD * 2);
  u16* Wzi_lo = (u16*)alloc((size_t)ZINN * ZD * 2);
  float* wtok = (float*)alloc((size_t)NP * 3 * 4);
  float* cb0 = (float*)alloc((size_t)NP * 4);
  float* token = (float*)alloc((size_t)BS * 4 * 4);

  // ---- prep ----
  k_pack_whh<<<dim3((NP * HIDN + 255) / 256), 256, 0, stream>>>(W_hh, Bpk);
  k_split<<<dim3((HIDN * ZD + 255) / 256), 256, 0, stream>>>(W_zh, Wzh_hi, Wzh_lo, HIDN * ZD);
  k_split<<<dim3((ZINN * ZD + 255) / 256), 256, 0, stream>>>(W_zi, Wzi_hi, Wzi_lo, ZINN * ZD);
  k_split<<<dim3((BS * ZD + 255) / 256), 256, 0, stream>>>(z, z_hi, z_lo, BS * ZD);
  k_prep_wih<<<dim3((NP * 128 + 255) / 256), 256, 0, stream>>>(W_ih, b_ih, b_hh, Wpk, wtok, cb0);
  k_token_init<<<dim3((BS * 4 + 255) / 256), 256, 0, stream>>>(init_input, token);

  // ---- prep GEMMs: h0 (Apk) and zin (Zpk) ----
  k_gemm<2><<<dim3(HIDN / 128, BS / 128), 256, 0, stream>>>(
      z_hi, z_lo, Wzh_hi, Wzh_lo, b_zh, Apk[0], HIDN, ZD);
  k_gemm<3><<<dim3(ZINN / 128, BS / 128), 256, 0, stream>>>(
      z_hi, z_lo, Wzi_hi, Wzi_lo, b_zi, Zpk, ZINN, ZD);

  // ---- 32 recurrent steps ----
  for (int t = 0; t < NST; ++t) {
    const int cur = t & 1, nxt = (t + 1) & 1;
    k_fused15<<<dim3(NP / 192, BS / 128), 512, 0, stream>>>(
        Apk[cur], Bpk, Zpk, Wpk, token, wtok, cb0, b_hh, Apk[nxt]);
    k_out<<<dim3(BS / 4), 256, 0, stream>>>(Apk[nxt], W_out, b_out, out, token, t);
  }
  (void)in_sizes; (void)n_in; (void)out_size; (void)ws_size;
}

// Round 16
// 1578.759 us; speedup vs baseline: 1.3641x; 1.3641x over previous
//
#include <hip/hip_runtime.h>
#include <hip/hip_bf16.h>
#include <math.h>

#define BS   4096
#define ZD   512
#define HIDN 1024
#define ZINN 128
#define NST  32
#define NP   3072   // 3*HIDN, gate-interleaved column space (96 = 3x32 groups)

typedef unsigned short u16;
typedef __bf16 bf16x8 __attribute__((ext_vector_type(8)));
typedef _Float16 f16x8 __attribute__((ext_vector_type(8)));
typedef float f32x4 __attribute__((ext_vector_type(4)));
typedef float f32x16 __attribute__((ext_vector_type(16)));

static __device__ __forceinline__ u16 bf_bits(float v) {
  __bf16 b = (__bf16)v;
  return __builtin_bit_cast(unsigned short, b);
}
static __device__ __forceinline__ float bf_val(float v) {
  return (float)(__bf16)v;
}
static __device__ __forceinline__ u16 h16_bits(float v) {
  _Float16 h = (_Float16)v;
  return __builtin_bit_cast(unsigned short, h);
}
static __device__ __forceinline__ float h16_val_bits(u16 b) {
  return (float)__builtin_bit_cast(_Float16, b);
}

// fast transcendentals on the hardware exp2 pipe (v_exp_f32, ~1 ulp)
static __device__ __forceinline__ float exp2_fast(float x) {
#if __has_builtin(__builtin_amdgcn_exp2f)
  return __builtin_amdgcn_exp2f(x);
#else
  return exp2f(x);
#endif
}
static __device__ __forceinline__ float sigmoid_fast(float x) {
  return 1.0f / (1.0f + exp2_fast(-1.4426950408889634f * x));
}
static __device__ __forceinline__ float tanh_fast(float x) {
  // tanh(x) = 1 - 2/(1 + exp(2x)); exp(2x) = exp2(2*log2e*x)
  return 1.0f - 2.0f / (1.0f + exp2_fast(2.8853900817779268f * x));
}

// async global -> LDS, 16 bytes per lane. LDS dest = wave-uniform base + lane*16.
static __device__ __forceinline__ void ld_lds16(const u16* g, u16* l) {
  __builtin_amdgcn_global_load_lds(
      (const __attribute__((address_space(1))) void*)g,
      (__attribute__((address_space(3))) void*)l, 16, 0, 0);
}

// W' row w -> original W_hh/W_ih row. 32-granular interleave for 32x32 MFMA:
// w = g*96 + j*32 + m  ->  j*1024 + g*32 + m   (j = gate r/u/n, m = h-col within group)
static __device__ __forceinline__ int r_orig(int w) {
  const int g = w / 96;
  const int rem = w - g * 96;
  const int j = rem >> 5, m = rem & 31;
  return j * 1024 + g * 32 + m;
}

// ---------------- fragment-major packed layouts (single f16 pass) ----------------
// 64-q (K=1024 operands): [rg = row/32][q = k/16][64 lanes x 8 u16].
// Lane slot l = ((k>>3)&1)*32 + (row&31) = the mfma_32x32x16 fragment order ->
// ds_read_b128 at base+lane*16 IS the fragment (0 conflicts, verified v6-v14);
// global_load_lds staging is linear 1KB blocks.
static __device__ __forceinline__ size_t pk_off(int row, int col) {
  return ((size_t)(row >> 5) * 64 + (col >> 4)) * 512 +
         (((col >> 3) & 1) * 32 + (row & 31)) * 8 + (col & 7);
}
// 8-q variant (K=128 operands: zin / Wihz)
static __device__ __forceinline__ size_t pkz_off(int row, int col) {
  return ((size_t)(row >> 5) * 8 + (col >> 4)) * 512 +
         (((col >> 3) & 1) * 32 + (row & 31)) * 8 + (col & 7);
}

// ---------------- prep kernels ----------------

__global__ void k_split(const float* __restrict__ s, u16* __restrict__ hi,
                        u16* __restrict__ lo, int n) {
  int i = blockIdx.x * 256 + threadIdx.x;
  if (i >= n) return;
  float v = s[i];
  float h = bf_val(v);
  hi[i] = bf_bits(v);
  lo[i] = bf_bits(v - h);
}

// W_hh -> fragment-major single-pass f16 Bpk with gate-interleaved row reorder
__global__ void k_pack_whh(const float* __restrict__ W_hh, u16* __restrict__ Bpk) {
  int i = blockIdx.x * 256 + threadIdx.x;
  if (i >= NP * HIDN) return;
  const int w = i >> 10, k = i & 1023;
  const float v = W_hh[(size_t)r_orig(w) * HIDN + k];
  Bpk[pk_off(w, k)] = h16_bits(v);
}

// W_ih[:,3:131] -> f16 frag-major Wpk (reordered rows); [:,0:3] -> wtok; cb0
__global__ void k_prep_wih(const float* __restrict__ W_ih, const float* __restrict__ b_ih,
                           const float* __restrict__ b_hh,
                           u16* __restrict__ Wpk,
                           float* __restrict__ wtok, float* __restrict__ cb0) {
  int i = blockIdx.x * 256 + threadIdx.x;
  if (i < NP * 128) {
    const int w = i >> 7, c = i & 127;
    const float v = W_ih[r_orig(w) * 131 + 3 + c];
    Wpk[pkz_off(w, c)] = h16_bits(v);
  }
  if (i < NP * 3) {
    const int w = i / 3, s = i - w * 3;
    wtok[i] = W_ih[r_orig(w) * 131 + s];
  }
  if (i < NP) {
    const int r = r_orig(i);
    cb0[i] = b_ih[r] + (r < 2048 ? b_hh[r] : 0.0f);
  }
}

__global__ void k_token_init(const float* __restrict__ init_input, float* __restrict__ token) {
  int i = blockIdx.x * 256 + threadIdx.x;
  if (i < BS * 4) token[i] = ((i & 3) < 3) ? init_input[i & 3] : 0.0f;
}

// ---------------- generic split-3 GEMM (prep only): C = A*B^T (+bias) ----------------
// OUTMODE: 2 = 64-q f16 Apk (h0);  3 = 8-q f16 Zpk (zin)
template <int OUTMODE>
__global__ __launch_bounds__(256) void k_gemm(
    const u16* __restrict__ Ahi, const u16* __restrict__ Alo,
    const u16* __restrict__ Bhi, const u16* __restrict__ Blo,
    const float* __restrict__ bias,
    u16* __restrict__ Apk, int N, int K) {
  __shared__ __align__(16) u16 sAhi[128 * 64];
  __shared__ __align__(16) u16 sAlo[128 * 64];
  __shared__ __align__(16) u16 sBhi[128 * 64];
  __shared__ __align__(16) u16 sBlo[128 * 64];

  const int t = threadIdx.x;
  const int row0 = blockIdx.y * 128, col0 = blockIdx.x * 128;
  const int wave = t >> 6, lane = t & 63;
  const int w64 = wave * 64;
  const int wm = (wave & 1) * 64, wn = (wave >> 1) * 64;
  const int lm = lane & 15, lq = lane >> 4;
  const int pb = lm & 7;

  f32x4 acc[4][4] = {};

  int sm[4], skc[4], sub[4];
#pragma unroll
  for (int i = 0; i < 4; ++i) {
    const int u = i * 256 + t;
    sm[i] = u >> 3;
    skc[i] = (u & 7) ^ (sm[i] & 7);
    sub[i] = (i * 256 + w64) * 8;
  }

  const int nk = K >> 6;
  for (int kt = 0; kt < nk; ++kt) {
    const int k0 = kt << 6;
    __syncthreads();
#pragma unroll
    for (int i = 0; i < 4; ++i) {
      const size_t ga = (size_t)(row0 + sm[i]) * K + k0 + skc[i] * 8;
      const size_t gb = (size_t)(col0 + sm[i]) * K + k0 + skc[i] * 8;
      ld_lds16(Ahi + ga, &sAhi[sub[i]]);
      ld_lds16(Alo + ga, &sAlo[sub[i]]);
      ld_lds16(Bhi + gb, &sBhi[sub[i]]);
      ld_lds16(Blo + gb, &sBlo[sub[i]]);
    }
    __syncthreads();
#pragma unroll
    for (int kk = 0; kk < 2; ++kk) {
      const int pos = ((kk * 4 + lq) ^ pb) * 8;
      bf16x8 ah[4], al[4], bh[4], bl[4];
#pragma unroll
      for (int i = 0; i < 4; ++i) {
        const int ma = (wm + i * 16 + lm) * 64;
        const int mb = (wn + i * 16 + lm) * 64;
        ah[i] = *(const bf16x8*)&sAhi[ma + pos];
        al[i] = *(const bf16x8*)&sAlo[ma + pos];
        bh[i] = *(const bf16x8*)&sBhi[mb + pos];
        bl[i] = *(const bf16x8*)&sBlo[mb + pos];
      }
#pragma unroll
      for (int i = 0; i < 4; ++i)
#pragma unroll
        for (int j = 0; j < 4; ++j) {
          acc[i][j] = __builtin_amdgcn_mfma_f32_16x16x32_bf16(ah[i], bh[j], acc[i][j], 0, 0, 0);
          acc[i][j] = __builtin_amdgcn_mfma_f32_16x16x32_bf16(al[i], bh[j], acc[i][j], 0, 0, 0);
          acc[i][j] = __builtin_amdgcn_mfma_f32_16x16x32_bf16(ah[i], bl[j], acc[i][j], 0, 0, 0);
        }
    }
  }

#pragma unroll
  for (int i = 0; i < 4; ++i) {
    const int grow = row0 + wm + i * 16 + lq * 4;
#pragma unroll
    for (int j = 0; j < 4; ++j) {
      const int gcol = col0 + wn + j * 16 + lm;
      const float bs = bias ? bias[gcol] : 0.0f;
#pragma unroll
      for (int d = 0; d < 4; ++d) {
        const float v = acc[i][j][d] + bs;
        if (OUTMODE == 2) {
          Apk[pk_off(grow + d, gcol)] = h16_bits(v);
        }
        if (OUTMODE == 3) {
          Apk[pkz_off(grow + d, gcol)] = h16_bits(v);
        }
      }
    }
  }
}

// ---------------- fused gh+gi GEMM + GRU gate kernel (v16 = v14 + fast transcendentals) ----------------
// v14's proven structure (BK=64 dbuf 80KB, 2 blk/CU, 8 waves 4Mx2N, one __syncthreads
// per tile, Z-fold, f16-only state, LDS-staged A AND B). v15's B-direct REVERTED
// (63.9us: per-kk dependent global loads exposed L2 latency the LDS shadow hides).
// NEW: epilogue sigmoid/tanh on the hardware exp2 pipe (v_exp_f32) instead of libm
// expf/tanhf — ~2x fewer VALU instructions in the GRU gate math.

#define SZA8 (128 * 64)   // 8192 u16/buf: [4 rg][4 q][512]
#define SZB8 (192 * 64)   // 12288 u16/buf: [6 rg][4 q][512]
#define MF8(a, b, c) c = __builtin_amdgcn_mfma_f32_32x32x16_f16(a, b, c, 0, 0, 0)

__global__ __launch_bounds__(512, 4) void k_fused16(
    const u16* __restrict__ Apk,   // f16 frag-major h [128 rg][64 q][512]
    const u16* __restrict__ Bpk,   // f16 frag-major Whh' [96 rg][64 q][512]
    const u16* __restrict__ Zpk,   // f16 frag-major zin [128 rg][8 q][512]
    const u16* __restrict__ Wpk,   // f16 frag-major Wihz' [96 rg][8 q][512]
    const float* __restrict__ token,
    const float* __restrict__ wtok,
    const float* __restrict__ cb0,
    const float* __restrict__ b_hh,
    u16* __restrict__ Apk_out) {
  __shared__ __align__(16) u16 sA[2 * SZA8];
  __shared__ __align__(16) u16 sB[2 * SZB8];

  const int t = threadIdx.x;
  const int wave = t >> 6, lane = t & 63;
  const int row0 = blockIdx.y * 128;
  const int colW0 = blockIdx.x * 192;
  const int wm = (wave >> 1) * 32;   // 4 M-waves x 32 rows
  const int wn = (wave & 1) * 96;    // 2 N-waves x 96 W-rows (one gate-triple group)
  const int lr = lane & 31, lh = lane >> 5;

  f32x16 acc0 = {}, acc1 = {}, acc2 = {}, acc3 = {};

  // ---- staging: 16 A blocks + 24 B blocks per BK=64 tile, 5 loads/wave ----
  const u16* asrc = Apk + ((size_t)((row0 >> 5) + (wave >> 1)) * 64 + (wave & 1) * 2) * 512 + lane * 8;
  const int aw = (wave >> 1) * 2048 + (wave & 1) * 1024;
  const int id0 = wave * 3, id1 = id0 + 1, id2 = id0 + 2;
  const u16* bsrc0 = Bpk + ((size_t)((colW0 >> 5) + (id0 >> 2)) * 64 + (id0 & 3)) * 512 + lane * 8;
  const u16* bsrc1 = Bpk + ((size_t)((colW0 >> 5) + (id1 >> 2)) * 64 + (id1 & 3)) * 512 + lane * 8;
  const u16* bsrc2 = Bpk + ((size_t)((colW0 >> 5) + (id2 >> 2)) * 64 + (id2 & 3)) * 512 + lane * 8;
  const int bw0 = id0 * 512, bw1 = id1 * 512, bw2 = id2 * 512;
  // Z-region sources (8-q layout)
  const u16* azb = Zpk + ((size_t)((row0 >> 5) + (wave >> 1)) * 8 + (wave & 1) * 2) * 512 + lane * 8;
  const u16* bzb0 = Wpk + ((size_t)((colW0 >> 5) + (id0 >> 2)) * 8 + (id0 & 3)) * 512 + lane * 8;
  const u16* bzb1 = Wpk + ((size_t)((colW0 >> 5) + (id1 >> 2)) * 8 + (id1 & 3)) * 512 + lane * 8;
  const u16* bzb2 = Wpk + ((size_t)((colW0 >> 5) + (id2 >> 2)) * 8 + (id2 & 3)) * 512 + lane * 8;

#define STAGE(kt_, ab, bb)                                            \
  ld_lds16(asrc + (size_t)(kt_) * 2048,       &sA[(ab) + aw]);        \
  ld_lds16(asrc + (size_t)(kt_) * 2048 + 512, &sA[(ab) + aw + 512]);  \
  ld_lds16(bsrc0 + (size_t)(kt_) * 2048, &sB[(bb) + bw0]);            \
  ld_lds16(bsrc1 + (size_t)(kt_) * 2048, &sB[(bb) + bw1]);            \
  ld_lds16(bsrc2 + (size_t)(kt_) * 2048, &sB[(bb) + bw2]);

#define STAGE_Z(zt_, ab, bb)                                          \
  ld_lds16(azb + (zt_) * 2048,       &sA[(ab) + aw]);                 \
  ld_lds16(azb + (zt_) * 2048 + 512, &sA[(ab) + aw + 512]);           \
  ld_lds16(bzb0 + (zt_) * 2048, &sB[(bb) + bw0]);                     \
  ld_lds16(bzb1 + (zt_) * 2048, &sB[(bb) + bw1]);                     \
  ld_lds16(bzb2 + (zt_) * 2048, &sB[(bb) + bw2]);

  // ---- fragment read bases (lane-linear) ----
  const int agA = (wave >> 1) * 2048;    // + kk*512
  const int bgB = (wave & 1) * 6144;     // + j*2048 + kk*512
  const int l8 = lane * 8;

  STAGE(0, 0, 0);
  __syncthreads();

#pragma unroll 1
  for (int kt = 0; kt < 16; ++kt) {
    const int ab = (kt & 1) ? SZA8 : 0, bb = (kt & 1) ? SZB8 : 0;
    const int an = (kt & 1) ? 0 : SZA8, bn = (kt & 1) ? 0 : SZB8;
    if (kt < 15) { STAGE(kt + 1, an, bn); }
    else         { STAGE_Z(0, an, bn); }
#pragma unroll
    for (int kk = 0; kk < 4; ++kk) {
      const f16x8 a = *(const f16x8*)&sA[ab + agA + kk * 512 + l8];
      const int kb = bb + bgB + kk * 512 + l8;
      const f16x8 b0 = *(const f16x8*)&sB[kb];
      const f16x8 b1 = *(const f16x8*)&sB[kb + 2048];
      const f16x8 b2 = *(const f16x8*)&sB[kb + 4096];
      MF8(a, b0, acc0); MF8(a, b1, acc1); MF8(a, b2, acc2);
    }
    __syncthreads();
  }
  // ---- Z tile 0 (zin cols 0..63) in buf0; n-gate -> acc3 ----
  STAGE_Z(1, SZA8, SZB8);
#pragma unroll
  for (int kk = 0; kk < 4; ++kk) {
    const f16x8 a = *(const f16x8*)&sA[agA + kk * 512 + l8];
    const int kb = bgB + kk * 512 + l8;
    const f16x8 b0 = *(const f16x8*)&sB[kb];
    const f16x8 b1 = *(const f16x8*)&sB[kb + 2048];
    const f16x8 b2 = *(const f16x8*)&sB[kb + 4096];
    MF8(a, b0, acc0); MF8(a, b1, acc1); MF8(a, b2, acc3);
  }
  __syncthreads();
  // ---- Z tile 1 (zin cols 64..127) in buf1 ----
#pragma unroll
  for (int kk = 0; kk < 4; ++kk) {
    const f16x8 a = *(const f16x8*)&sA[SZA8 + agA + kk * 512 + l8];
    const int kb = SZB8 + bgB + kk * 512 + l8;
    const f16x8 b0 = *(const f16x8*)&sB[kb];
    const f16x8 b1 = *(const f16x8*)&sB[kb + 2048];
    const f16x8 b2 = *(const f16x8*)&sB[kb + 4096];
    MF8(a, b0, acc0); MF8(a, b1, acc1); MF8(a, b2, acc3);
  }
#undef STAGE
#undef STAGE_Z

  // ---- fused GRU epilogue (f32 math on hw-exp2; f16 carry) ----
  const int w0 = colW0 + wn + lr;                  // W'-row of r-gate
  const int c = ((colW0 + wn) / 96) * 32 + lr;     // h-col
  float wt[3][3];
#pragma unroll
  for (int j = 0; j < 3; ++j) {
    wt[j][0] = wtok[(w0 + j * 32) * 3 + 0];
    wt[j][1] = wtok[(w0 + j * 32) * 3 + 1];
    wt[j][2] = wtok[(w0 + j * 32) * 3 + 2];
  }
  const float cbr = cb0[w0], cbu = cb0[w0 + 32], cbn = cb0[w0 + 64];
  const float bnn = b_hh[2048 + c];
  const int cq = c >> 4, ckh = (c >> 3) & 1, ce = c & 7;
#pragma unroll
  for (int d = 0; d < 16; ++d) {
    const int row = row0 + wm + 4 * lh + (d & 3) + 8 * (d >> 2);
    const float4 tk = *(const float4*)&token[row * 4];
    const float pr = cbr + acc0[d] + tk.x * wt[0][0] + tk.y * wt[0][1] + tk.z * wt[0][2];
    const float pu = cbu + acc1[d] + tk.x * wt[1][0] + tk.y * wt[1][1] + tk.z * wt[1][2];
    const float pin = cbn + acc3[d] + tk.x * wt[2][0] + tk.y * wt[2][1] + tk.z * wt[2][2];
    const float hn = acc2[d] + bnn;
    const float r = sigmoid_fast(pr);
    const float u = sigmoid_fast(pu);
    const float n = tanh_fast(pin + r * hn);
    const size_t poff = ((size_t)(row >> 5) * 64 + cq) * 512 + (ckh * 32 + (row & 31)) * 8 + ce;
    const float ho = h16_val_bits(Apk[poff]);
    const float hv = (1.0f - u) * n + u * ho;
    Apk_out[poff] = h16_bits(hv);
  }
}
#undef MF8

// ---------------- per-step output kernel (reads packed f16 h; v11-proven) ----------------
__global__ __launch_bounds__(256) void k_out(
    const u16* __restrict__ Apk, const float* __restrict__ W_out,
    const float* __restrict__ b_out,
    float* __restrict__ out, float* __restrict__ token, int step) {
  const int wave = threadIdx.x >> 6, lane = threadIdx.x & 63;
  const int row = blockIdx.x * 4 + wave;
  const u16* base = Apk + (size_t)(row >> 5) * 64 * 512 + (row & 31) * 8;
  float s0 = 0.f, s1 = 0.f, s2 = 0.f;
#pragma unroll
  for (int cc = 0; cc < 2; ++cc) {
    const int ch = lane + cc * 64;   // 16B chunk id, k = ch*8 + e
    const f16x8 hv = *(const f16x8*)&base[(ch >> 1) * 512 + (ch & 1) * 256];
    const int k0 = ch * 8;
#pragma unroll
    for (int e = 0; e < 8; ++e) {
      const float hf = (float)hv[e];
      s0 += hf * W_out[k0 + e];
      s1 += hf * W_out[1024 + k0 + e];
      s2 += hf * W_out[2048 + k0 + e];
    }
  }
#pragma unroll
  for (int off = 32; off > 0; off >>= 1) {
    s0 += __shfl_xor(s0, off, 64);
    s1 += __shfl_xor(s1, off, 64);
    s2 += __shfl_xor(s2, off, 64);
  }
  if (lane == 0) {
    const float o0 = s0 + b_out[0];
    const float o1 = s1 + b_out[1];
    const float o2 = s2 + b_out[2];
    const float bass = sigmoid_fast(o0);
    const float rhy = sigmoid_fast(o2);
    const size_t ob = ((size_t)row * NST + step) * 3;
    out[ob + 0] = bass;
    out[ob + 1] = o1;
    out[ob + 2] = rhy;
    token[row * 4 + 0] = bass;
    token[row * 4 + 1] = o1;
    token[row * 4 + 2] = (rhy > 0.5f) ? 1.0f : 0.0f;
  }
}

// ---------------- host ----------------
extern "C" void kernel_launch(void* const* d_in, const int* in_sizes, int n_in,
                              void* d_out, int out_size, void* d_ws, size_t ws_size,
                              hipStream_t stream) {
  const float* z = (const float*)d_in[0];
  const float* W_zh = (const float*)d_in[3];
  const float* b_zh = (const float*)d_in[4];
  const float* W_zi = (const float*)d_in[5];
  const float* b_zi = (const float*)d_in[6];
  const float* W_ih = (const float*)d_in[7];
  const float* b_ih = (const float*)d_in[8];
  const float* W_hh = (const float*)d_in[9];
  const float* b_hh = (const float*)d_in[10];
  const float* W_out = (const float*)d_in[11];
  const float* b_out = (const float*)d_in[12];
  const float* init_input = (const float*)d_in[13];
  float* out = (float*)d_out;

  char* p = (char*)d_ws;
  auto alloc = [&](size_t bytes) {
    char* q = p;
    p += (bytes + 255) & ~(size_t)255;
    return q;
  };
  u16* Apk[2];
  for (int s = 0; s < 2; ++s) {
    Apk[s] = (u16*)alloc((size_t)BS * 1024 * 2);
  }
  u16* Bpk = (u16*)alloc((size_t)NP * 1024 * 2);
  u16* Zpk = (u16*)alloc((size_t)BS * 128 * 2);
  u16* Wpk = (u16*)alloc((size_t)NP * 128 * 2);
  u16* z_hi = (u16*)alloc((size_t)BS * ZD * 2);
  u16* z_lo = (u16*)alloc((size_t)BS * ZD * 2);
  u16* Wzh_hi = (u16*)alloc((size_t)HIDN * ZD * 2);
  u16* Wzh_lo = (u16*)alloc((size_t)HIDN * ZD * 2);
  u16* Wzi_hi = (u16*)alloc((size_t)ZINN * ZD * 2);
  u16* Wzi_lo = (u16*)alloc((size_t)ZINN * ZD * 2);
  float* wtok = (float*)alloc((size_t)NP * 3 * 4);
  float* cb0 = (float*)alloc((size_t)NP * 4);
  float* token = (float*)alloc((size_t)BS * 4 * 4);

  // ---- prep ----
  k_pack_whh<<<dim3((NP * HIDN + 255) / 256), 256, 0, stream>>>(W_hh, Bpk);
  k_split<<<dim3((HIDN * ZD + 255) / 256), 256, 0, stream>>>(W_zh, Wzh_hi, Wzh_lo, HIDN * ZD);
  k_split<<<dim3((ZINN * ZD + 255) / 256), 256, 0, stream>>>(W_zi, Wzi_hi, Wzi_lo, ZINN * ZD);
  k_split<<<dim3((BS * ZD + 255) / 256), 256, 0, stream>>>(z, z_hi, z_lo, BS * ZD);
  k_prep_wih<<<dim3((NP * 128 + 255) / 256), 256, 0, stream>>>(W_ih, b_ih, b_hh, Wpk, wtok, cb0);
  k_token_init<<<dim3((BS * 4 + 255) / 256), 256, 0, stream>>>(init_input, token);

  // ---- prep GEMMs: h0 (Apk) and zin (Zpk) ----
  k_gemm<2><<<dim3(HIDN / 128, BS / 128), 256, 0, stream>>>(
      z_hi, z_lo, Wzh_hi, Wzh_lo, b_zh, Apk[0], HIDN, ZD);
  k_gemm<3><<<dim3(ZINN / 128, BS / 128), 256, 0, stream>>>(
      z_hi, z_lo, Wzi_hi, Wzi_lo, b_zi, Zpk, ZINN, ZD);

  // ---- 32 recurrent steps ----
  for (int t = 0; t < NST; ++t) {
    const int cur = t & 1, nxt = (t + 1) & 1;
    k_fused16<<<dim3(NP / 192, BS / 128), 512, 0, stream>>>(
        Apk[cur], Bpk, Zpk, Wpk, token, wtok, cb0, b_hh, Apk[nxt]);
    k_out<<<dim3(BS / 4), 256, 0, stream>>>(Apk[nxt], W_out, b_out, out, token, t);
  }
  (void)in_sizes; (void)n_in; (void)out_size; (void)ws_size;
}